// Round 4
// baseline (110.801 us; speedup 1.0000x reference)
//
#include <hip/hip_runtime.h>
#include <math.h>

#define CLS_NUM 16
#define NB 16
#define NH 160
#define NW 160
#define NCH 22          // 6 + CLS_NUM
#define CSZ 25600       // NH*NW channel plane
#define NT 2048
#define TPB 320         // 5 waves
#define ROWS 10         // rows per tile
#define KPT 5           // cells per thread (320*5 = 1600 = 10*160)
#define NBLK 256        // 16 batches x 16 tiles
#define CAP 2048        // LDS target capacity (worst case: all targets one batch)
#define EPS_F 1e-7f

// ws layout: partial[NBLK*64] floats, then counter (1 uint).
// partial is fully rewritten every call before any read (no zeroing needed).
// counter is never reset: any 256 consecutive increments contain exactly one
// old value == 255 (mod 256), so the finalize fires exactly once per call
// regardless of the counter's starting value (poison/replay safe).

__global__ __launch_bounds__(TPB) void detect_fused(
        const float* __restrict__ predict,
        const float* __restrict__ targets,
        float* __restrict__ out,
        float* __restrict__ partial,
        unsigned int* __restrict__ counter)
{
    __shared__ float tg[CAP * 7];     // cs,sn,x3,x4,y3,y4,class
    __shared__ float acc_s[64];       // per-class: aobj, anoobj, cobj, cnoobj
    __shared__ float fin[5][64];
    __shared__ int cnt_s;
    __shared__ int flag_s;

    const int tid  = threadIdx.x;
    const int tile = blockIdx.x;      // 0..15
    const int b    = blockIdx.y;      // 0..15
    const int bid  = b * 16 + tile;
    const int rb   = tile * ROWS;

    if (tid == 0) cnt_s = 0;
    if (tid < 64) acc_s[tid] = 0.0f;
    __syncthreads();

    // ---- phase 0: gather this batch's targets into LDS ----
    for (int n = tid; n < NT; n += TPB) {
        const float* tp = targets + n * 7;
        if ((int)tp[0] == b) {
            float cx = tp[2] * 0.125f, cy = tp[3] * 0.125f;
            float w  = tp[4] * 0.125f, h  = tp[5] * 0.125f;
            float ang = tp[6];
            float cs_ = cosf(ang), sn_ = sinf(ang);
            float xr =  cx * cs_ + cy * sn_;
            float yr = -cx * sn_ + cy * cs_;
            int slot = atomicAdd(&cnt_s, 1);
            float* g = tg + slot * 7;
            g[0] = cs_; g[1] = sn_;
            g[2] = xr - h * 0.5f; g[3] = xr + h * 0.5f;
            g[4] = yr - w * 0.5f; g[5] = yr + w * 0.5f;
            g[6] = tp[1];
        }
    }
    __syncthreads();
    const int cnt = cnt_s;

    // per-thread cell coordinates
    float gx[KPT], gy[KPT];
    #pragma unroll
    for (int k = 0; k < KPT; k++) {
        int cell = tid + k * TPB;
        gx[k] = (float)(cell % NW) + 0.5f;
        gy[k] = (float)(rb + cell / NW) + 0.5f;
    }

    // ---- phase 1: masks for all 16 classes (bit c = obj, bit 16+c = wide) ----
    unsigned m[KPT] = {0u, 0u, 0u, 0u, 0u};
    const float rbc = (float)rb + 5.0f;   // tile center y (10-row tile)
    for (int t = 0; t < cnt; t++) {
        const float* g = tg + t * 7;
        float cs_ = g[0], sn_ = g[1];
        float x3 = g[2], x4 = g[3], y3 = g[4], y4 = g[5];
        // block-uniform tile reject vs wide box (1e-3 slack vs rounding)
        float acs = fabsf(cs_), asn = fabsf(sn_);
        float ex = acs * 79.5f + asn * 4.5f + 1e-3f;
        float ey = acs * 4.5f  + asn * 79.5f + 1e-3f;
        float vxc = cs_ * 80.0f + sn_ * rbc;
        float vyc = cs_ * rbc   - sn_ * 80.0f;
        if (vxc + ex < x3 - 0.5f || vxc - ex > x4 + 0.5f ||
            vyc + ey < y3 - 0.5f || vyc - ey > y4 + 0.5f) continue;
        int cl = (int)g[6];
        #pragma unroll
        for (int k = 0; k < KPT; k++) {
            float vx = cs_ * gx[k] + sn_ * gy[k];
            float vy = cs_ * gy[k] - sn_ * gx[k];
            float mn = fminf(fminf(vx - x3, x4 - vx), fminf(vy - y3, y4 - vy));
            unsigned add = (mn >= 0.0f ? 1u : 0u) | (mn >= -0.5f ? 0x10000u : 0u);
            m[k] |= add << cl;
        }
    }

    // ---- phase 2: conf loss per class + raw-logit argmax ----
    const float* base = predict + (size_t)b * NCH * CSZ + rb * NW;
    float bestraw[KPT];
    int   bi[KPT];
    #pragma unroll
    for (int k = 0; k < KPT; k++) { bestraw[k] = -INFINITY; bi[k] = 0; }

    for (int c = 0; c < CLS_NUM; c++) {
        const float* cp = base + (size_t)(6 + c) * CSZ;
        float ao = 0.f, an = 0.f, co = 0.f, cn = 0.f;
        #pragma unroll
        for (int k = 0; k < KPT; k++) {
            float pv = cp[tid + k * TPB];
            if (pv > bestraw[k]) { bestraw[k] = pv; bi[k] = c; }  // strict > keeps first
            float s  = 1.0f / (1.0f + __expf(-pv));
            float sc = fminf(fmaxf(s, EPS_F), 1.0f - EPS_F);
            if ((m[k] >> c) & 1u)           { ao -= __logf(sc); co += 1.0f; }
            if (!((m[k] >> (16 + c)) & 1u)) { an -= __logf(1.0f - sc); cn += 1.0f; }
        }
        #pragma unroll
        for (int o = 32; o > 0; o >>= 1) {
            ao += __shfl_down(ao, o);
            an += __shfl_down(an, o);
            co += __shfl_down(co, o);
            cn += __shfl_down(cn, o);
        }
        if ((tid & 63) == 0) {
            atomicAdd(&acc_s[c * 4 + 0], ao);
            atomicAdd(&acc_s[c * 4 + 1], an);
            atomicAdd(&acc_s[c * 4 + 2], co);
            atomicAdd(&acc_s[c * 4 + 3], cn);
        }
    }

    // ---- phase 3: boxes ----
    #pragma unroll
    for (int k = 0; k < KPT; k++) {
        int cell = tid + k * TPB;
        float p0 = base[cell];
        float p1 = base[(size_t)1 * CSZ + cell];
        float p2 = base[(size_t)2 * CSZ + cell];
        float p3 = base[(size_t)3 * CSZ + cell];
        float p4 = base[(size_t)4 * CSZ + cell];
        float p5 = base[(size_t)5 * CSZ + cell];
        float x = 1.0f / (1.0f + __expf(-p0)) * 5.0f - 2.0f;
        float y = 1.0f / (1.0f + __expf(-p1)) * 5.0f - 2.0f;
        float p = 1.0f / (1.0f + __expf(-p4)) * 2.0f - 1.0f;
        float q = 1.0f / (1.0f + __expf(-p5)) * 2.0f - 1.0f;
        float best = 1.0f / (1.0f + __expf(-bestraw[k]));
        float tq = sqrtf((1.0f + p) * 0.5f + 1e-16f);
        float bang = atan2f(q / (2.0f * tq + 1e-16f), tq);
        int j = cell % NW;
        int i = rb + cell / NW;
        float* o = out + 1 + ((size_t)b * CSZ + (size_t)i * NW + j) * 7;
        o[0] = best;
        o[1] = (float)bi[k];
        o[2] = ((float)j + x) * 8.0f;
        o[3] = ((float)i + y) * 8.0f;
        o[4] = __expf(p2) * 8.0f;
        o[5] = __expf(p3) * 8.0f;
        o[6] = bang;
    }

    // ---- write partials; last block finalizes the loss ----
    __syncthreads();
    if (tid < 64) partial[bid * 64 + tid] = acc_s[tid];
    __threadfence();                       // release: partials visible device-wide
    __syncthreads();
    if (tid == 0) {
        unsigned old = atomicAdd(counter, 1u);
        flag_s = ((old & 255u) == 255u) ? 1 : 0;
    }
    __syncthreads();
    if (flag_s) {                          // block-uniform
        __threadfence();                   // acquire before reading partials
        int v = tid & 63, grp = tid >> 6;  // 5 wave-groups
        float s = 0.f;
        for (int bk = grp; bk < NBLK; bk += 5) s += partial[bk * 64 + v];
        fin[grp][v] = s;
        __syncthreads();
        if (tid < 64)
            acc_s[tid] = fin[0][tid] + fin[1][tid] + fin[2][tid] + fin[3][tid] + fin[4][tid];
        __syncthreads();
        if (tid == 0) {
            float L = 0.f;
            for (int c = 0; c < CLS_NUM; c++) {
                float ao = acc_s[c * 4 + 0], an = acc_s[c * 4 + 1];
                float co = acc_s[c * 4 + 2], cn = acc_s[c * 4 + 3];
                if (co > 0.0f) L += ao / fmaxf(co, 1.0f) + an / fmaxf(cn, 1.0f);
            }
            out[0] = L;
        }
    }
}

extern "C" void kernel_launch(void* const* d_in, const int* in_sizes, int n_in,
                              void* d_out, int out_size, void* d_ws, size_t ws_size,
                              hipStream_t stream) {
    const float* predict = (const float*)d_in[0];
    const float* targets = (const float*)d_in[1];
    float* out = (float*)d_out;

    float* partial = (float*)d_ws;                          // NBLK*64 floats
    unsigned int* counter = (unsigned int*)(partial + NBLK * 64);

    detect_fused<<<dim3(16, 16), TPB, 0, stream>>>(predict, targets, out,
                                                   partial, counter);
}

// Round 6
// 41.582 us; speedup vs baseline: 2.6647x; 2.6647x over previous
//
#include <hip/hip_runtime.h>
#include <math.h>

#define CLS_NUM 16
#define NB 16
#define NH 160
#define NW 160
#define NCH 22          // 6 + CLS_NUM
#define CSZ 25600       // NH*NW plane
#define NT 2048
#define TPB 256
#define NBOXU 1600      // boxes units (256 cells each)
#define NMASKU 2560     // mask units: 256 (c,b) pairs x 10 16-row tiles
#define CAP 256         // LDS capacity for matched targets per (pair,tile)
#define EPS_F 1e-7f

// ws: partial[NMASKU*4] floats (aobj, anoobj, cobj, cnoobj per unit).
// Fully rewritten every call before any read -> no zeroing, poison-safe.

__global__ __launch_bounds__(TPB) void detect_main(
        const float* __restrict__ predict,
        const float* __restrict__ targets,
        float* __restrict__ out,
        float* __restrict__ partial)
{
    __shared__ float tg[CAP][6];
    __shared__ float red_s[16];
    __shared__ int cnt_s;

    const int tid = threadIdx.x;
    const int bid = blockIdx.x;

    if (bid < NBOXU) {
        // ---------------- boxes unit ----------------
        int b = bid / 100;                     // 100 units per batch plane
        int r = (bid % 100) * TPB + tid;       // cell within plane
        const float* pb = predict + (size_t)b * NCH * CSZ + r;
        float p0 = pb[0];
        float p1 = pb[1 * CSZ];
        float p2 = pb[2 * CSZ];
        float p3 = pb[3 * CSZ];
        float p4 = pb[4 * CSZ];
        float p5 = pb[5 * CSZ];
        float bestraw = pb[6 * CSZ];
        int bi = 0;
        #pragma unroll
        for (int cc = 1; cc < CLS_NUM; cc++) {
            float v = pb[(6 + cc) * CSZ];
            if (v > bestraw) { bestraw = v; bi = cc; }   // strict >: first argmax
        }
        float x = 1.0f / (1.0f + __expf(-p0)) * 5.0f - 2.0f;
        float y = 1.0f / (1.0f + __expf(-p1)) * 5.0f - 2.0f;
        float p = 1.0f / (1.0f + __expf(-p4)) * 2.0f - 1.0f;
        float q = 1.0f / (1.0f + __expf(-p5)) * 2.0f - 1.0f;
        float best = 1.0f / (1.0f + __expf(-bestraw));   // sigmoid monotonic
        float tq = sqrtf((1.0f + p) * 0.5f + 1e-16f);
        float bang = atan2f(q / (2.0f * tq + 1e-16f), tq);
        int i = r / NW, j = r % NW;
        float* o = out + 1 + ((size_t)b * CSZ + r) * 7;
        o[0] = best;
        o[1] = (float)bi;
        o[2] = ((float)j + x) * 8.0f;
        o[3] = ((float)i + y) * 8.0f;
        o[4] = __expf(p2) * 8.0f;
        o[5] = __expf(p3) * 8.0f;
        o[6] = bang;
        return;
    }

    // ---------------- mask + conf-loss unit ----------------
    const int u = bid - NBOXU;
    const int pair = u / 10, tile = u - pair * 10;
    const int c = pair >> 4, b = pair & 15;
    const int rb = tile * 16;

    if (tid == 0) cnt_s = 0;
    __syncthreads();

    const float rbc = (float)rb + 8.0f;        // 16-row tile center
    const float rlo = (float)rb + 0.5f, rhi = (float)rb + 15.5f;

    // gather matching targets (stride-256 scan of raw target list)
    for (int n = tid; n < NT; n += TPB) {
        const float* tp = targets + n * 7;
        if ((int)tp[0] == b && (int)tp[1] == c) {
            float cx = tp[2] * 0.125f, cy = tp[3] * 0.125f;
            float w  = tp[4] * 0.125f, h  = tp[5] * 0.125f;
            // rotation-invariant row prefilter (R >= wide-box circumradius)
            float R = 0.5f * sqrtf(w * w + h * h) + 0.75f;
            if (cy + R >= rlo && cy - R <= rhi) {
                float ang = tp[6];
                float cs_ = cosf(ang), sn_ = sinf(ang);
                float xr =  cx * cs_ + cy * sn_;
                float yr = -cx * sn_ + cy * cs_;
                float x3 = xr - h * 0.5f, x4 = xr + h * 0.5f;
                float y3 = yr - w * 0.5f, y4 = yr + w * 0.5f;
                // block-uniform tile reject in rotated frame (validated r2/r3)
                float acs = fabsf(cs_), asn = fabsf(sn_);
                float ex = acs * 79.5f + asn * 7.5f + 1e-3f;
                float ey = acs * 7.5f  + asn * 79.5f + 1e-3f;
                float vxc = cs_ * 80.0f + sn_ * rbc;
                float vyc = cs_ * rbc   - sn_ * 80.0f;
                if (!(vxc + ex < x3 - 0.5f || vxc - ex > x4 + 0.5f ||
                      vyc + ey < y3 - 0.5f || vyc - ey > y4 + 0.5f)) {
                    int slot = atomicAdd(&cnt_s, 1);
                    if (slot < CAP) {
                        tg[slot][0] = cs_; tg[slot][1] = sn_;
                        tg[slot][2] = x3;  tg[slot][3] = x4;
                        tg[slot][4] = y3;  tg[slot][5] = y4;
                    }
                }
            }
        }
    }
    __syncthreads();
    const int cnt = min(cnt_s, CAP);

    // per-thread cell coordinates (10 cells each: 16 rows x 160 cols)
    float gx[10], gy[10];
    #pragma unroll
    for (int k = 0; k < 10; k++) {
        int cell = tid + k * TPB;
        gx[k] = (float)(cell % NW) + 0.5f;
        gy[k] = (float)(rb + cell / NW) + 0.5f;
    }

    unsigned objb = 0, wideb = 0;
    for (int t = 0; t < cnt; t++) {
        float cs_ = tg[t][0], sn_ = tg[t][1];
        float x3 = tg[t][2], x4 = tg[t][3], y3 = tg[t][4], y4 = tg[t][5];
        #pragma unroll
        for (int k = 0; k < 10; k++) {
            float vx = cs_ * gx[k] + sn_ * gy[k];
            float vy = cs_ * gy[k] - sn_ * gx[k];
            float mn = fminf(fminf(vx - x3, x4 - vx),
                             fminf(vy - y3, y4 - vy));
            objb  |= (mn >= 0.0f)  ? (1u << k) : 0u;
            wideb |= (mn >= -0.5f) ? (1u << k) : 0u;
        }
    }

    const float* cp = predict + ((size_t)(b * NCH + 6 + c)) * CSZ + rb * NW;
    float ao = 0.f, an = 0.f;
    #pragma unroll
    for (int k = 0; k < 10; k++) {
        float pv = cp[tid + k * TPB];
        float s  = 1.0f / (1.0f + __expf(-pv));
        float sc = fminf(fmaxf(s, EPS_F), 1.0f - EPS_F);
        if ((objb >> k) & 1u)     ao -= __logf(sc);
        if (!((wideb >> k) & 1u)) an -= __logf(1.0f - sc);
    }
    float co = (float)__popc(objb);
    float cn = (float)__popc(~wideb & 0x3FFu);
    #pragma unroll
    for (int o = 32; o > 0; o >>= 1) {
        ao += __shfl_down(ao, o);
        an += __shfl_down(an, o);
        co += __shfl_down(co, o);
        cn += __shfl_down(cn, o);
    }
    if ((tid & 63) == 0) {
        int wid = tid >> 6;
        red_s[wid * 4 + 0] = ao; red_s[wid * 4 + 1] = an;
        red_s[wid * 4 + 2] = co; red_s[wid * 4 + 3] = cn;
    }
    __syncthreads();
    if (tid < 4) {
        float s = red_s[tid] + red_s[4 + tid] + red_s[8 + tid] + red_s[12 + tid];
        partial[u * 4 + tid] = s;
    }
}

// 1 block, 256 threads: reduce partial[2560][4] -> loss -> out[0]
__global__ __launch_bounds__(256) void finalize_kernel(
        const float* __restrict__ partial,
        float* __restrict__ out)
{
    __shared__ float fin_s[4][64];
    int tid = threadIdx.x;
    int v = tid & 63, g = tid >> 6;       // 64 (class,comp) slots x 4 groups
    int c2 = v >> 2, comp = v & 3;
    float s = 0.f;
    for (int i = 0; i < 40; i++)          // class c2 owns units [c2*160, c2*160+160)
        s += partial[(c2 * 160 + g * 40 + i) * 4 + comp];
    fin_s[g][v] = s;
    __syncthreads();
    if (tid < 64)
        fin_s[0][tid] = fin_s[0][tid] + fin_s[1][tid] + fin_s[2][tid] + fin_s[3][tid];
    __syncthreads();
    if (tid == 0) {
        float L = 0.f;
        for (int c = 0; c < CLS_NUM; c++) {
            float ao = fin_s[0][c * 4 + 0], an = fin_s[0][c * 4 + 1];
            float co = fin_s[0][c * 4 + 2], cn = fin_s[0][c * 4 + 3];
            if (co > 0.f) L += ao / fmaxf(co, 1.f) + an / fmaxf(cn, 1.f);
        }
        out[0] = L;
    }
}

extern "C" void kernel_launch(void* const* d_in, const int* in_sizes, int n_in,
                              void* d_out, int out_size, void* d_ws, size_t ws_size,
                              hipStream_t stream) {
    const float* predict = (const float*)d_in[0];
    const float* targets = (const float*)d_in[1];
    float* out = (float*)d_out;
    float* partial = (float*)d_ws;              // NMASKU*4 floats

    detect_main<<<NBOXU + NMASKU, TPB, 0, stream>>>(predict, targets, out, partial);
    finalize_kernel<<<1, 256, 0, stream>>>(partial, out);
}